// Round 5
// baseline (72.542 us; speedup 1.0000x reference)
//
#include <hip/hip_runtime.h>

// query_depth_point: B=8, N=16384, M=2048, NSAMPLE=64, DIS_Z=0.5
// R8 probe: TWO queries per wave (q0=2p, q1=2p+1) sharing every z1 load.
// 512-candidate groups (candidate = g + 8*lane + j, lex in (lane,j)),
// ballot + prefix-popcount ordered ranking, per-query wave-uniform skip
// once saturated, loop exits when both queries have 64 matches.
// Depth-1 group prefetch (2 float4 in flight), wrap addressing.
// 8192 waves total = exactly one residency round (8 waves/SIMD).
// Outputs int32: idx (B,M,64) then pts_cnt (B,M).
// Discriminating probe: if kernel-attributable time is large (~28us),
// expect dur_us ~58-65; if window is harness-floor, expect ~72 unchanged.

#define QDP_B 8
#define QDP_N 16384
#define QDP_M 2048
#define QDP_NS 64
#define QDP_DISZ 0.5f

__device__ __forceinline__ void qdp_group(
    int g, float zq, const float4& A, const float4& B,
    int lane, unsigned long long below,
    int& cnt, int& firstv, int* __restrict__ idx_out)
{
    const bool m0 = fabsf(A.x - zq) < QDP_DISZ;
    const bool m1 = fabsf(A.y - zq) < QDP_DISZ;
    const bool m2 = fabsf(A.z - zq) < QDP_DISZ;
    const bool m3 = fabsf(A.w - zq) < QDP_DISZ;
    const bool m4 = fabsf(B.x - zq) < QDP_DISZ;
    const bool m5 = fabsf(B.y - zq) < QDP_DISZ;
    const bool m6 = fabsf(B.z - zq) < QDP_DISZ;
    const bool m7 = fabsf(B.w - zq) < QDP_DISZ;

    const unsigned long long b0 = __ballot(m0);
    const unsigned long long b1 = __ballot(m1);
    const unsigned long long b2 = __ballot(m2);
    const unsigned long long b3 = __ballot(m3);
    const unsigned long long b4 = __ballot(m4);
    const unsigned long long b5 = __ballot(m5);
    const unsigned long long b6 = __ballot(m6);
    const unsigned long long b7 = __ballot(m7);
    const unsigned long long any = b0|b1|b2|b3|b4|b5|b6|b7;
    if (!any) return;                                   // wave-uniform

    const int mbyte = (int)m0 | ((int)m1<<1) | ((int)m2<<2) | ((int)m3<<3)
                    | ((int)m4<<4) | ((int)m5<<5) | ((int)m6<<6) | ((int)m7<<7);
    if (cnt == 0) {
        const int l0  = (int)__builtin_ctzll(any);
        const int mb0 = __shfl(mbyte, l0);
        firstv = g + 8 * l0 + (int)__builtin_ctz((unsigned)mb0);
    }
    int r = cnt + __popcll(b0 & below) + __popcll(b1 & below)
                + __popcll(b2 & below) + __popcll(b3 & below)
                + __popcll(b4 & below) + __popcll(b5 & below)
                + __popcll(b6 & below) + __popcll(b7 & below);
    const int base = g + 8 * lane;
    if (m0) { if (r < QDP_NS) idx_out[r] = base + 0; r++; }
    if (m1) { if (r < QDP_NS) idx_out[r] = base + 1; r++; }
    if (m2) { if (r < QDP_NS) idx_out[r] = base + 2; r++; }
    if (m3) { if (r < QDP_NS) idx_out[r] = base + 3; r++; }
    if (m4) { if (r < QDP_NS) idx_out[r] = base + 4; r++; }
    if (m5) { if (r < QDP_NS) idx_out[r] = base + 5; r++; }
    if (m6) { if (r < QDP_NS) idx_out[r] = base + 6; r++; }
    if (m7) { if (r < QDP_NS) idx_out[r] = base + 7; r++; }
    cnt += __popcll(b0) + __popcll(b1) + __popcll(b2) + __popcll(b3)
         + __popcll(b4) + __popcll(b5) + __popcll(b6) + __popcll(b7);
}

__global__ __launch_bounds__(256) void QueryDepthPoint_kernel(
    const float* __restrict__ xyz1,   // (B,3,N)
    const float* __restrict__ xyz2,   // (B,3,M)
    int* __restrict__ out_idx,        // (B,M,NS) int32
    int* __restrict__ out_cnt)        // (B,M)    int32
{
    const int lane = threadIdx.x & 63;
    const int wid  = (blockIdx.x << 2) + (threadIdx.x >> 6);   // 4 waves/block
                                                               // wid in [0, 8192)
    const int b  = wid >> 10;            // 1024 query-pairs per batch
    const int q0 = (wid & 1023) << 1;    // queries q0, q0+1

    const float* __restrict__ z2 = xyz2 + b * 3 * QDP_M + 2 * QDP_M;
    const float zq0 = z2[q0];
    const float zq1 = z2[q0 + 1];
    const float* __restrict__ z1 = xyz1 + b * 3 * QDP_N + 2 * QDP_N;

    const int qbase = (b << 11) + q0;                 // b*M + q0
    int* __restrict__ idx0 = out_idx + (size_t)qbase * QDP_NS;
    int* __restrict__ idx1 = idx0 + QDP_NS;

    int cnt0 = 0, firstv0 = 0;
    int cnt1 = 0, firstv1 = 0;
    const unsigned long long below = (1ull << lane) - 1ull;
    const int lo = 8 * lane;            // lane's offset within a 512-group

    // group 0: 512 candidates via 2 independent 16B loads
    float4 cA = ((const float4*)(z1 + lo))[0];
    float4 cB = ((const float4*)(z1 + lo))[1];

    #pragma unroll 1   // 32 trips x large body: do not unroll
    for (int g = 0; g < QDP_N; g += 512) {
        // depth-1 prefetch of group g+1 (wrap: always in-bounds)
        const int pn = (g + 512) & (QDP_N - 1);
        const float4 nA = ((const float4*)(z1 + pn + lo))[0];
        const float4 nB = ((const float4*)(z1 + pn + lo))[1];

        // both branches are wave-uniform (cnt is identical across lanes)
        if (cnt0 < QDP_NS) qdp_group(g, zq0, cA, cB, lane, below, cnt0, firstv0, idx0);
        if (cnt1 < QDP_NS) qdp_group(g, zq1, cA, cB, lane, below, cnt1, firstv1, idx1);
        if (cnt0 >= QDP_NS && cnt1 >= QDP_NS) break;

        cA = nA; cB = nB;
    }
    if (cnt0 > QDP_NS) cnt0 = QDP_NS;
    if (cnt1 > QDP_NS) cnt1 = QDP_NS;

    // trailing slots [cnt, 64) get the first-match index (0 if no match)
    if (lane >= cnt0) idx0[lane] = firstv0;
    if (lane >= cnt1) idx1[lane] = firstv1;
    if (lane < 2)     out_cnt[qbase + lane] = lane ? cnt1 : cnt0;
}

extern "C" void kernel_launch(void* const* d_in, const int* in_sizes, int n_in,
                              void* d_out, int out_size, void* d_ws, size_t ws_size,
                              hipStream_t stream) {
    const float* xyz1 = (const float*)d_in[0];   // (B,3,N) fp32
    const float* xyz2 = (const float*)d_in[1];   // (B,3,M) fp32
    int* out = (int*)d_out;                      // idx (B*M*64) then pts_cnt (B*M)

    int* out_idx = out;
    int* out_cnt = out + (size_t)QDP_B * QDP_M * QDP_NS;

    const int total_waves = (QDP_B * QDP_M) / 2;     // 8192 waves, 2 queries each
    const int grid = total_waves / 4;                // 4 waves (256 thr) per block

    QueryDepthPoint_kernel<<<grid, 256, 0, stream>>>(xyz1, xyz2, out_idx, out_cnt);
}